// Round 1
// baseline (2490.214 us; speedup 1.0000x reference)
//
#include <hip/hip_runtime.h>

#define N_TOKENS   65536
#define NUM_CODES  4096
#define EMBED_DIM  256

#define BM 64      // tokens per block (k_argmin)
#define BK 64      // codes per chunk
#define DS 64      // d-slice staged in LDS
#define LDSTR 68   // padded LDS row stride in dwords (64 + 4)

// out layout (all f32): z_q [N*D], indices [N], loss, perplexity
#define IDX_OFF  ((size_t)N_TOKENS * EMBED_DIM)
#define LOSS_OFF (IDX_OFF + N_TOKENS)

// ---------------- kernel 1: per-code squared norms ----------------
__global__ void k_esq(const float* __restrict__ E, float* __restrict__ esq) {
    int k = blockIdx.x;
    int l = threadIdx.x;                       // 64 lanes
    float4 v = *(const float4*)(E + (size_t)k * EMBED_DIM + l * 4);
    float s = v.x * v.x + v.y * v.y + v.z * v.z + v.w * v.w;
    #pragma unroll
    for (int off = 32; off; off >>= 1) s += __shfl_down(s, off, 64);
    if (l == 0) esq[k] = s;
}

// ---------------- kernel 2: fused distance + argmin (exact fp32) ----------------
__launch_bounds__(256)
__global__ void k_argmin(const float* __restrict__ Z, const float* __restrict__ E,
                         const float* __restrict__ esq, int* __restrict__ out_idx) {
    __shared__ float zs[BM * LDSTR];
    __shared__ float es[BK * LDSTR];
    __shared__ float esq_s[BK];

    const int tid  = threadIdx.x;
    const int tcol = tid & 15;    // code group 0..15
    const int trow = tid >> 4;    // token group 0..15
    const int tok0 = blockIdx.x * BM;

    float best[4];
    int   bidx[4];
    #pragma unroll
    for (int i = 0; i < 4; ++i) { best[i] = 3.4e38f; bidx[i] = 0; }

    for (int c0 = 0; c0 < NUM_CODES; c0 += BK) {
        float acc[4][4];
        #pragma unroll
        for (int i = 0; i < 4; ++i)
            #pragma unroll
            for (int j = 0; j < 4; ++j) acc[i][j] = 0.0f;

        for (int d0 = 0; d0 < EMBED_DIM; d0 += DS) {
            __syncthreads();   // prior slice reads complete before restage
            // stage z slice: BM x DS floats = 1024 float4s over 256 threads
            for (int f = tid; f < BM * DS / 4; f += 256) {
                int r = f >> 4, c4 = f & 15;
                float4 v = *(const float4*)(Z + (size_t)(tok0 + r) * EMBED_DIM + d0 + c4 * 4);
                *(float4*)(zs + r * LDSTR + c4 * 4) = v;
            }
            // stage e slice: BK x DS
            for (int f = tid; f < BK * DS / 4; f += 256) {
                int r = f >> 4, c4 = f & 15;
                float4 v = *(const float4*)(E + (size_t)(c0 + r) * EMBED_DIM + d0 + c4 * 4);
                *(float4*)(es + r * LDSTR + c4 * 4) = v;
            }
            if (d0 == 0 && tid < BK) esq_s[tid] = esq[c0 + tid];
            __syncthreads();

            // 4x4 register micro-tile over this slice
            for (int d4 = 0; d4 < DS / 4; ++d4) {
                float4 zv[4], ev[4];
                #pragma unroll
                for (int i = 0; i < 4; ++i)
                    zv[i] = *(const float4*)(zs + (trow * 4 + i) * LDSTR + d4 * 4);
                #pragma unroll
                for (int j = 0; j < 4; ++j)
                    ev[j] = *(const float4*)(es + (tcol + 16 * j) * LDSTR + d4 * 4);
                #pragma unroll
                for (int i = 0; i < 4; ++i)
                    #pragma unroll
                    for (int j = 0; j < 4; ++j) {
                        acc[i][j] = fmaf(zv[i].x, ev[j].x, acc[i][j]);
                        acc[i][j] = fmaf(zv[i].y, ev[j].y, acc[i][j]);
                        acc[i][j] = fmaf(zv[i].z, ev[j].z, acc[i][j]);
                        acc[i][j] = fmaf(zv[i].w, ev[j].w, acc[i][j]);
                    }
            }
        }
        // chunk complete: running argmin on (e_sq - 2*dot), codes ascending in-thread
        #pragma unroll
        for (int j = 0; j < 4; ++j) {
            int code = c0 + tcol + 16 * j;
            float eq = esq_s[tcol + 16 * j];
            #pragma unroll
            for (int i = 0; i < 4; ++i) {
                float v = fmaf(-2.0f, acc[i][j], eq);
                if (v < best[i]) { best[i] = v; bidx[i] = code; }
            }
        }
    }

    // reduce across the 16 tcol lanes of each token group (lanes trow*16..+15)
    #pragma unroll
    for (int i = 0; i < 4; ++i) {
        float v = best[i] + 512.0f;   // keep positive so uint bits are monotone
        unsigned long long p =
            ((unsigned long long)__float_as_uint(v) << 32) | (unsigned)bidx[i];
        #pragma unroll
        for (int m = 8; m; m >>= 1) {
            unsigned long long q = __shfl_xor(p, m, 64);
            p = (q < p) ? q : p;    // ties -> smallest index (matches argmin)
        }
        if (tcol == 0) out_idx[tok0 + trow * 4 + i] = (int)(p & 0xFFFFFFFFu);
    }
}

// ---------------- kernel 3: gather z_q, loss partials, histogram ----------------
__global__ void k_gather(const float* __restrict__ Z, const float* __restrict__ E,
                         const int* __restrict__ idx, float* __restrict__ out,
                         float* __restrict__ loss_parts, unsigned* __restrict__ hist) {
    int wave = threadIdx.x >> 6, lane = threadIdx.x & 63;
    int token = blockIdx.x * 4 + wave;
    int k = idx[token];
    float4 z = *(const float4*)(Z + (size_t)token * EMBED_DIM + lane * 4);
    float4 q = *(const float4*)(E + (size_t)k * EMBED_DIM + lane * 4);
    *(float4*)(out + (size_t)token * EMBED_DIM + lane * 4) = q;  // z_q_st == z_q
    float dx = q.x - z.x, dy = q.y - z.y, dz = q.z - z.z, dw = q.w - z.w;
    float s = dx * dx + dy * dy + dz * dz + dw * dw;
    #pragma unroll
    for (int off = 32; off; off >>= 1) s += __shfl_down(s, off, 64);
    if (lane == 0) {
        atomicAdd(loss_parts + (blockIdx.x & 1023), s);
        atomicAdd(hist + k, 1u);
        out[IDX_OFF + token] = (float)k;
    }
}

// ---------------- kernel 4: finalize loss + perplexity ----------------
__global__ void k_final(const float* __restrict__ loss_parts,
                        const unsigned* __restrict__ hist, float* __restrict__ out) {
    __shared__ float red[256];
    int t = threadIdx.x;
    float s = 0.0f;
    for (int i = t; i < 1024; i += 256) s += loss_parts[i];
    red[t] = s;
    __syncthreads();
    #pragma unroll
    for (int off = 128; off; off >>= 1) {
        if (t < off) red[t] += red[t + off];
        __syncthreads();
    }
    float loss = 0.1f * red[0] / (float)(N_TOKENS * EMBED_DIM);

    float h = 0.0f;
    for (int i = t; i < NUM_CODES; i += 256) {
        float p = (float)hist[i] / (float)N_TOKENS;
        h += p * logf(p + 1e-10f);
    }
    __syncthreads();
    red[t] = h;
    __syncthreads();
    #pragma unroll
    for (int off = 128; off; off >>= 1) {
        if (t < off) red[t] += red[t + off];
        __syncthreads();
    }
    if (t == 0) {
        out[LOSS_OFF]     = loss;
        out[LOSS_OFF + 1] = expf(-red[0]);
    }
}

extern "C" void kernel_launch(void* const* d_in, const int* in_sizes, int n_in,
                              void* d_out, int out_size, void* d_ws, size_t ws_size,
                              hipStream_t stream) {
    const float* Z = (const float*)d_in[0];   // z_e [65536,256]
    const float* E = (const float*)d_in[1];   // embeddings [4096,256]
    float* out = (float*)d_out;
    char* ws = (char*)d_ws;

    // ws layout
    float*    esq        = (float*)ws;                          // 16 KB
    int*      idx        = (int*)(ws + 16384);                  // 256 KB
    float*    loss_parts = (float*)(ws + 16384 + 262144);       // 4 KB
    unsigned* hist       = (unsigned*)(ws + 16384 + 262144 + 4096); // 16 KB

    // zero loss partials + histogram (contiguous 20 KB)
    hipMemsetAsync(loss_parts, 0, 4096 + 16384, stream);

    k_esq   <<<NUM_CODES, 64, 0, stream>>>(E, esq);
    k_argmin<<<N_TOKENS / BM, 256, 0, stream>>>(Z, E, esq, idx);
    k_gather<<<N_TOKENS / 4, 256, 0, stream>>>(Z, E, idx, out, loss_parts, hist);
    k_final <<<1, 256, 0, stream>>>(loss_parts, hist, out);
}

// Round 2
// 557.386 us; speedup vs baseline: 4.4677x; 4.4677x over previous
//
#include <hip/hip_runtime.h>

#define N_TOKENS   65536
#define NUM_CODES  4096
#define EMBED_DIM  256

#define IDX_OFF  ((size_t)N_TOKENS * EMBED_DIM)
#define LOSS_OFF (IDX_OFF + N_TOKENS)

#define DELTA 0.2f
#define UCAP  16384

typedef _Float16 half8 __attribute__((ext_vector_type(8)));
typedef float    f32x4 __attribute__((ext_vector_type(4)));
typedef unsigned long long u64;

// swizzled tile layouts (fp16):
//  Zh[tokblock=512][kc=8][r=128][g'=4][8]   g' = g ^ ((r>>1)&3)
//  Eh[codeblock=32][kc=8][r=128][g'=4][8]
// each [kc] slab is 8 KB, lane-linear for global_load_lds.

__device__ __forceinline__ void gl_lds16(const void* g, void* l) {
    __builtin_amdgcn_global_load_lds(
        (const __attribute__((address_space(1))) unsigned int*)g,
        (__attribute__((address_space(3))) unsigned int*)l, 16, 0, 0);
}

// ---------------- converters: f32 -> swizzled fp16 tiles ----------------
__global__ void k_conv(const float* __restrict__ X, _Float16* __restrict__ Xh, int nrows) {
    int gid = blockIdx.x * 256 + threadIdx.x;           // nrows*32 threads
    int n  = gid >> 5;
    int kg = gid & 31;                                   // 8-elem group
    if (n >= nrows) return;
    const float* src = X + (size_t)n * EMBED_DIM + kg * 8;
    float4 a = *(const float4*)src;
    float4 b = *(const float4*)(src + 4);
    int tb = n >> 7, r = n & 127, kc = kg >> 2, g = kg & 3;
    int gp = g ^ ((r >> 1) & 3);
    half8 hv;
    hv[0]=(_Float16)a.x; hv[1]=(_Float16)a.y; hv[2]=(_Float16)a.z; hv[3]=(_Float16)a.w;
    hv[4]=(_Float16)b.x; hv[5]=(_Float16)b.y; hv[6]=(_Float16)b.z; hv[7]=(_Float16)b.w;
    *(half8*)(Xh + (size_t)tb * 32768 + kc * 4096 + r * 32 + gp * 8) = hv;
}

// ---------------- per-code squared norms (exact fp32) ----------------
__global__ void k_esq(const float* __restrict__ E, float* __restrict__ esq) {
    int k = blockIdx.x;
    int l = threadIdx.x;
    float4 v = *(const float4*)(E + (size_t)k * EMBED_DIM + l * 4);
    float s = v.x * v.x + v.y * v.y + v.z * v.z + v.w * v.w;
    #pragma unroll
    for (int off = 32; off; off >>= 1) s += __shfl_down(s, off, 64);
    if (l == 0) esq[k] = s;
}

// ---------------- transpose E -> Et[256][4096] (for refine) ----------------
__global__ void k_transpose(const float* __restrict__ E, float* __restrict__ Et) {
    __shared__ float t[32][33];
    int tx = threadIdx.x & 31, ty = threadIdx.x >> 5;   // 32x8
    int c0 = blockIdx.x * 32, d0 = blockIdx.y * 32;
    #pragma unroll
    for (int i = 0; i < 4; ++i)
        t[ty + 8 * i][tx] = E[(size_t)(c0 + ty + 8 * i) * EMBED_DIM + d0 + tx];
    __syncthreads();
    #pragma unroll
    for (int i = 0; i < 4; ++i)
        Et[(size_t)(d0 + ty + 8 * i) * NUM_CODES + c0 + tx] = t[tx][ty + 8 * i];
}

// ---------------- fused fp16-MFMA distance + argmin/second ----------------
__launch_bounds__(256, 2)
__global__ void k_argmin_mfma(const _Float16* __restrict__ Zh, const _Float16* __restrict__ Eh,
                              const float* __restrict__ esq, int* __restrict__ out_idx,
                              int* __restrict__ ulist, int* __restrict__ ucount) {
    __shared__ __align__(16) _Float16 As[4096];  // 8 KB: current A chunk
    __shared__ __align__(16) _Float16 Bs[4096];  // 8 KB: current B chunk

    const int tid  = threadIdx.x;
    const int lane = tid & 63;
    const int w    = tid >> 6;       // wave 0..3
    const int w0   = w >> 1;         // row half
    const int w1   = w & 1;          // col half
    const int l15  = lane & 15;
    const int q    = lane >> 4;
    const int tb   = blockIdx.x;     // token block (128 tokens)

    // constant fragment LDS byte offsets (swizzled)
    int aoff[4], boff[4];
    #pragma unroll
    for (int i = 0; i < 4; ++i) {
        int r = w0 * 64 + i * 16 + l15;
        aoff[i] = r * 64 + ((q ^ ((r >> 1) & 3)) * 16);
    }
    #pragma unroll
    for (int j = 0; j < 4; ++j) {
        int c = w1 * 64 + j * 16 + l15;
        boff[j] = c * 64 + ((q ^ ((c >> 1) & 3)) * 16);
    }

    float best[16], sec[16];
    int   bidx[16];
    #pragma unroll
    for (int k = 0; k < 16; ++k) { best[k] = 1e30f; sec[k] = 1e30f; bidx[k] = 0; }

    const _Float16* Zt = Zh + (size_t)tb * 32768;

    for (int it = 0; it < 32; ++it) {
        const _Float16* Et = Eh + (size_t)it * 32768;
        f32x4 acc[4][4];
        #pragma unroll
        for (int i = 0; i < 4; ++i)
            #pragma unroll
            for (int j = 0; j < 4; ++j) acc[i][j] = (f32x4)0.0f;

        for (int kc = 0; kc < 8; ++kc) {
            __syncthreads();
            // stage A + B chunks (each wave: 4 x 1 KB direct-to-LDS)
            const _Float16* ga = Zt + kc * 4096 + w * 1024 + lane * 8;
            const _Float16* gb = Et + kc * 4096 + w * 1024 + lane * 8;
            gl_lds16(ga,       As + w * 1024);
            gl_lds16(ga + 512, As + w * 1024 + 512);
            gl_lds16(gb,       Bs + w * 1024);
            gl_lds16(gb + 512, Bs + w * 1024 + 512);
            __syncthreads();

            half8 af[4], bf[4];
            #pragma unroll
            for (int i = 0; i < 4; ++i)
                af[i] = *(const half8*)((const char*)As + aoff[i]);
            #pragma unroll
            for (int j = 0; j < 4; ++j)
                bf[j] = *(const half8*)((const char*)Bs + boff[j]);
            #pragma unroll
            for (int i = 0; i < 4; ++i)
                #pragma unroll
                for (int j = 0; j < 4; ++j)
                    acc[i][j] = __builtin_amdgcn_mfma_f32_16x16x32_f16(af[i], bf[j], acc[i][j], 0, 0, 0);
        }

        // epilogue: d2 = esq - 2*dot ; update per-lane best/second
        int cbase = it * 128 + w1 * 64 + l15;
        #pragma unroll
        for (int j = 0; j < 4; ++j) {
            float e  = esq[cbase + j * 16];
            int code = cbase + j * 16;
            #pragma unroll
            for (int i = 0; i < 4; ++i)
                #pragma unroll
                for (int r = 0; r < 4; ++r) {
                    float v = fmaf(-2.0f, acc[i][j][r], e);
                    int k = i * 4 + r;
                    float ob = best[k];
                    bool t = v < ob;
                    best[k] = t ? v : ob;
                    sec[k]  = fminf(sec[k], t ? ob : v);
                    bidx[k] = t ? code : bidx[k];
                }
        }
    }

    // butterfly merge across the 16 col-lanes of each quad group
    #pragma unroll
    for (int m = 1; m <= 8; m <<= 1) {
        #pragma unroll
        for (int k = 0; k < 16; ++k) {
            float ob = __shfl_xor(best[k], m, 64);
            float os = __shfl_xor(sec[k],  m, 64);
            int   oi = __shfl_xor(bidx[k], m, 64);
            float ns = fminf(fminf(sec[k], os), fmaxf(best[k], ob));
            bool t = (ob < best[k]) || (ob == best[k] && oi < bidx[k]);
            best[k] = t ? ob : best[k];
            bidx[k] = t ? oi : bidx[k];
            sec[k]  = ns;
        }
    }

    // cross-wave-column merge via LDS scratch (reuse As)
    __syncthreads();
    float* mb = (float*)As;          // [128][2]
    float* ms = mb + 256;
    int*   mi = (int*)(mb + 512);
    if (l15 == 0) {
        #pragma unroll
        for (int k = 0; k < 16; ++k) {
            int row = w0 * 64 + (k >> 2) * 16 + q * 4 + (k & 3);
            mb[row * 2 + w1] = best[k];
            ms[row * 2 + w1] = sec[k];
            mi[row * 2 + w1] = bidx[k];
        }
    }
    __syncthreads();
    if (tid < 128) {
        float b0 = mb[tid * 2], b1 = mb[tid * 2 + 1];
        float s0 = ms[tid * 2], s1 = ms[tid * 2 + 1];
        int   i0 = mi[tid * 2], i1 = mi[tid * 2 + 1];
        bool t = (b1 < b0) || (b1 == b0 && i1 < i0);
        float bb = t ? b1 : b0;
        int   ii = t ? i1 : i0;
        float ss = fminf(fminf(s0, s1), fmaxf(b0, b1));
        int token = tb * 128 + tid;
        out_idx[token] = ii;
        if (ss - bb < DELTA) {
            int p = atomicAdd(ucount, 1);
            if (p < UCAP) ulist[p] = token;
        }
    }
}

// ---------------- exact fp32 re-scan of uncertain tokens ----------------
__global__ void k_refine(const float* __restrict__ Z, const float* __restrict__ Et,
                         const float* __restrict__ esq, const int* __restrict__ ulist,
                         const int* __restrict__ ucount, int* __restrict__ out_idx) {
    __shared__ float zs[8][256];
    __shared__ u64 redu[4][8];
    const int tid = threadIdx.x;
    const int lane = tid & 63, w = tid >> 6;
    int cnt = *ucount; if (cnt > UCAP) cnt = UCAP;

    for (int base = blockIdx.x * 8; base < cnt; base += 256 * 8) {
        int valid = cnt - base; if (valid > 8) valid = 8;
        // stage z for valid tokens
        for (int t = 0; t < valid; ++t) {
            int tok = ulist[base + t];
            zs[t][tid] = Z[(size_t)tok * EMBED_DIM + tid];
        }
        __syncthreads();

        u64 pk[8];
        #pragma unroll
        for (int t = 0; t < 8; ++t) pk[t] = ~0ull;

        for (int pass = 0; pass < 16; ++pass) {
            int c = pass * 256 + tid;
            float acc[8];
            #pragma unroll
            for (int t = 0; t < 8; ++t) acc[t] = 0.0f;
            for (int d4 = 0; d4 < 64; ++d4) {
                float e0 = Et[(size_t)(d4 * 4 + 0) * NUM_CODES + c];
                float e1 = Et[(size_t)(d4 * 4 + 1) * NUM_CODES + c];
                float e2 = Et[(size_t)(d4 * 4 + 2) * NUM_CODES + c];
                float e3 = Et[(size_t)(d4 * 4 + 3) * NUM_CODES + c];
                #pragma unroll
                for (int t = 0; t < 8; ++t) {
                    float4 z4 = *(const float4*)&zs[t][d4 * 4];
                    acc[t] = fmaf(z4.x, e0, acc[t]);
                    acc[t] = fmaf(z4.y, e1, acc[t]);
                    acc[t] = fmaf(z4.z, e2, acc[t]);
                    acc[t] = fmaf(z4.w, e3, acc[t]);
                }
            }
            float eq = esq[c];
            #pragma unroll
            for (int t = 0; t < 8; ++t) {
                float v = fmaf(-2.0f, acc[t], eq) + 4096.0f;   // keep positive
                u64 p = ((u64)__float_as_uint(v) << 32) | (unsigned)c;
                pk[t] = p < pk[t] ? p : pk[t];
            }
        }
        // reduce across 256 threads
        #pragma unroll
        for (int t = 0; t < 8; ++t) {
            u64 p = pk[t];
            #pragma unroll
            for (int m = 1; m <= 32; m <<= 1) {
                u64 o = __shfl_xor(p, m, 64);
                p = o < p ? o : p;
            }
            if (lane == 0) redu[w][t] = p;
        }
        __syncthreads();
        if (tid < 8 && tid < valid) {
            u64 p = redu[0][tid];
            if (redu[1][tid] < p) p = redu[1][tid];
            if (redu[2][tid] < p) p = redu[2][tid];
            if (redu[3][tid] < p) p = redu[3][tid];
            out_idx[ulist[base + tid]] = (int)(p & 0xFFFFFFFFu);
        }
        __syncthreads();
    }
}

// ---------------- gather z_q, loss partials, histogram ----------------
__global__ void k_gather(const float* __restrict__ Z, const float* __restrict__ E,
                         float* __restrict__ out,
                         float* __restrict__ loss_parts, unsigned* __restrict__ hist) {
    int wave = threadIdx.x >> 6, lane = threadIdx.x & 63;
    int token = blockIdx.x * 4 + wave;
    int* idxi = (int*)(out + IDX_OFF);
    int k = idxi[token];
    float4 z = *(const float4*)(Z + (size_t)token * EMBED_DIM + lane * 4);
    float4 qv = *(const float4*)(E + (size_t)k * EMBED_DIM + lane * 4);
    *(float4*)(out + (size_t)token * EMBED_DIM + lane * 4) = qv;
    float dx = qv.x - z.x, dy = qv.y - z.y, dz = qv.z - z.z, dw = qv.w - z.w;
    float s = dx * dx + dy * dy + dz * dz + dw * dw;
    #pragma unroll
    for (int off = 32; off; off >>= 1) s += __shfl_down(s, off, 64);
    if (lane == 0) {
        atomicAdd(loss_parts + (blockIdx.x & 1023), s);
        atomicAdd(hist + k, 1u);
        out[IDX_OFF + token] = (float)k;   // in-place int -> float
    }
}

// ---------------- finalize loss + perplexity ----------------
__global__ void k_final(const float* __restrict__ loss_parts,
                        const unsigned* __restrict__ hist, float* __restrict__ out) {
    __shared__ float red[256];
    int t = threadIdx.x;
    float s = 0.0f;
    for (int i = t; i < 1024; i += 256) s += loss_parts[i];
    red[t] = s;
    __syncthreads();
    #pragma unroll
    for (int off = 128; off; off >>= 1) {
        if (t < off) red[t] += red[t + off];
        __syncthreads();
    }
    float loss = 0.1f * red[0] / (float)(N_TOKENS * EMBED_DIM);

    float h = 0.0f;
    for (int i = t; i < NUM_CODES; i += 256) {
        float p = (float)hist[i] / (float)N_TOKENS;
        h += p * logf(p + 1e-10f);
    }
    __syncthreads();
    red[t] = h;
    __syncthreads();
    #pragma unroll
    for (int off = 128; off; off >>= 1) {
        if (t < off) red[t] += red[t + off];
        __syncthreads();
    }
    if (t == 0) {
        out[LOSS_OFF]     = loss;
        out[LOSS_OFF + 1] = expf(-red[0]);
    }
}

extern "C" void kernel_launch(void* const* d_in, const int* in_sizes, int n_in,
                              void* d_out, int out_size, void* d_ws, size_t ws_size,
                              hipStream_t stream) {
    const float* Z = (const float*)d_in[0];
    const float* E = (const float*)d_in[1];
    float* out = (float*)d_out;
    char*  ob  = (char*)d_out;
    char*  ws  = (char*)d_ws;

    // scratch inside d_out (rewritten by gather/final afterwards):
    _Float16* Zh = (_Float16*)ob;                         // 32 MB
    _Float16* Eh = (_Float16*)(ob + 33554432);            // 2 MB
    float*    Et = (float*)(ob + 33554432 + 2097152);     // 4 MB
    int*      idx = (int*)(out + IDX_OFF);                // final index slot (in-place)

    // small ws scratch (~100 KB)
    float*    esq        = (float*)ws;                    // 16 KB
    int*      ulist      = (int*)(ws + 16384);            // 64 KB
    int*      ucount     = (int*)(ws + 81920);            // 64 B
    float*    loss_parts = (float*)(ws + 81984);          // 4 KB
    unsigned* hist       = (unsigned*)(ws + 86080);       // 16 KB

    hipMemsetAsync(ws + 81920, 0, 64 + 4096 + 16384, stream);

    k_conv       <<<(N_TOKENS * 32) / 256, 256, 0, stream>>>(Z, Zh, N_TOKENS);
    k_conv       <<<(NUM_CODES * 32) / 256, 256, 0, stream>>>(E, Eh, NUM_CODES);
    k_esq        <<<NUM_CODES, 64, 0, stream>>>(E, esq);
    k_transpose  <<<dim3(NUM_CODES / 32, EMBED_DIM / 32), 256, 0, stream>>>(E, Et);
    k_argmin_mfma<<<N_TOKENS / 128, 256, 0, stream>>>(Zh, Eh, esq, idx, ulist, ucount);
    k_refine     <<<256, 256, 0, stream>>>(Z, Et, esq, ulist, ucount, idx);
    k_gather     <<<N_TOKENS / 4, 256, 0, stream>>>(Z, E, out, loss_parts, hist);
    k_final      <<<1, 256, 0, stream>>>(loss_parts, hist, out);
}

// Round 3
// 399.157 us; speedup vs baseline: 6.2387x; 1.3964x over previous
//
#include <hip/hip_runtime.h>

#define N_TOKENS   65536
#define NUM_CODES  4096
#define EMBED_DIM  256

#define IDX_OFF  ((size_t)N_TOKENS * EMBED_DIM)
#define LOSS_OFF (IDX_OFF + N_TOKENS)

#define DELTA 0.2f
#define UCAP  16384
#define RT    8        // tokens per refine block

typedef _Float16 half8 __attribute__((ext_vector_type(8)));
typedef float    f32x4 __attribute__((ext_vector_type(4)));
typedef unsigned long long u64;

// swizzled tile layouts (fp16):
//  Zh[tokblock=512][kc=8][r=128][g'=4][8]   g' = g ^ ((r>>1)&3)
//  Eh[codeblock=32][kc=8][r=128][g'=4][8]

__device__ __forceinline__ void gl_lds16(const void* g, void* l) {
    __builtin_amdgcn_global_load_lds(
        (const __attribute__((address_space(1))) unsigned int*)g,
        (__attribute__((address_space(3))) unsigned int*)l, 16, 0, 0);
}

// ---------------- converters: f32 -> swizzled fp16 tiles ----------------
__global__ void k_conv(const float* __restrict__ X, _Float16* __restrict__ Xh, int nrows) {
    int gid = blockIdx.x * 256 + threadIdx.x;
    int n  = gid >> 5;
    int kg = gid & 31;
    if (n >= nrows) return;
    const float* src = X + (size_t)n * EMBED_DIM + kg * 8;
    float4 a = *(const float4*)src;
    float4 b = *(const float4*)(src + 4);
    int tb = n >> 7, r = n & 127, kc = kg >> 2, g = kg & 3;
    int gp = g ^ ((r >> 1) & 3);
    half8 hv;
    hv[0]=(_Float16)a.x; hv[1]=(_Float16)a.y; hv[2]=(_Float16)a.z; hv[3]=(_Float16)a.w;
    hv[4]=(_Float16)b.x; hv[5]=(_Float16)b.y; hv[6]=(_Float16)b.z; hv[7]=(_Float16)b.w;
    *(half8*)(Xh + (size_t)tb * 32768 + kc * 4096 + r * 32 + gp * 8) = hv;
}

// ---------------- per-code squared norms (exact fp32) ----------------
__global__ void k_esq(const float* __restrict__ E, float* __restrict__ esq) {
    int k = blockIdx.x;
    int l = threadIdx.x;
    float4 v = *(const float4*)(E + (size_t)k * EMBED_DIM + l * 4);
    float s = v.x * v.x + v.y * v.y + v.z * v.z + v.w * v.w;
    #pragma unroll
    for (int off = 32; off; off >>= 1) s += __shfl_down(s, off, 64);
    if (l == 0) esq[k] = s;
}

// ---------------- transpose E -> Et[256][4096] (for refine) ----------------
__global__ void k_transpose(const float* __restrict__ E, float* __restrict__ Et) {
    __shared__ float t[32][33];
    int tx = threadIdx.x & 31, ty = threadIdx.x >> 5;
    int c0 = blockIdx.x * 32, d0 = blockIdx.y * 32;
    #pragma unroll
    for (int i = 0; i < 4; ++i)
        t[ty + 8 * i][tx] = E[(size_t)(c0 + ty + 8 * i) * EMBED_DIM + d0 + tx];
    __syncthreads();
    #pragma unroll
    for (int i = 0; i < 4; ++i)
        Et[(size_t)(d0 + ty + 8 * i) * NUM_CODES + c0 + tx] = t[tx][ty + 8 * i];
}

// ---------------- fused fp16-MFMA distance + argmin/second ----------------
__launch_bounds__(256, 2)
__global__ void k_argmin_mfma(const _Float16* __restrict__ Zh, const _Float16* __restrict__ Eh,
                              const float* __restrict__ esq, int* __restrict__ out_idx,
                              int* __restrict__ ulist, int* __restrict__ ucount) {
    __shared__ __align__(16) _Float16 As[4096];
    __shared__ __align__(16) _Float16 Bs[4096];

    const int tid  = threadIdx.x;
    const int lane = tid & 63;
    const int w    = tid >> 6;
    const int w0   = w >> 1;
    const int w1   = w & 1;
    const int l15  = lane & 15;
    const int q    = lane >> 4;
    const int tb   = blockIdx.x;

    int aoff[4], boff[4];
    #pragma unroll
    for (int i = 0; i < 4; ++i) {
        int r = w0 * 64 + i * 16 + l15;
        aoff[i] = r * 64 + ((q ^ ((r >> 1) & 3)) * 16);
    }
    #pragma unroll
    for (int j = 0; j < 4; ++j) {
        int c = w1 * 64 + j * 16 + l15;
        boff[j] = c * 64 + ((q ^ ((c >> 1) & 3)) * 16);
    }

    float best[16], sec[16];
    int   bidx[16];
    #pragma unroll
    for (int k = 0; k < 16; ++k) { best[k] = 1e30f; sec[k] = 1e30f; bidx[k] = 0; }

    const _Float16* Zt = Zh + (size_t)tb * 32768;

    for (int it = 0; it < 32; ++it) {
        const _Float16* Et = Eh + (size_t)it * 32768;
        f32x4 acc[4][4];
        #pragma unroll
        for (int i = 0; i < 4; ++i)
            #pragma unroll
            for (int j = 0; j < 4; ++j) acc[i][j] = (f32x4)0.0f;

        for (int kc = 0; kc < 8; ++kc) {
            __syncthreads();
            const _Float16* ga = Zt + kc * 4096 + w * 1024 + lane * 8;
            const _Float16* gb = Et + kc * 4096 + w * 1024 + lane * 8;
            gl_lds16(ga,       As + w * 1024);
            gl_lds16(ga + 512, As + w * 1024 + 512);
            gl_lds16(gb,       Bs + w * 1024);
            gl_lds16(gb + 512, Bs + w * 1024 + 512);
            __syncthreads();

            half8 af[4], bf[4];
            #pragma unroll
            for (int i = 0; i < 4; ++i)
                af[i] = *(const half8*)((const char*)As + aoff[i]);
            #pragma unroll
            for (int j = 0; j < 4; ++j)
                bf[j] = *(const half8*)((const char*)Bs + boff[j]);
            #pragma unroll
            for (int i = 0; i < 4; ++i)
                #pragma unroll
                for (int j = 0; j < 4; ++j)
                    acc[i][j] = __builtin_amdgcn_mfma_f32_16x16x32_f16(af[i], bf[j], acc[i][j], 0, 0, 0);
        }

        int cbase = it * 128 + w1 * 64 + l15;
        #pragma unroll
        for (int j = 0; j < 4; ++j) {
            float e  = esq[cbase + j * 16];
            int code = cbase + j * 16;
            #pragma unroll
            for (int i = 0; i < 4; ++i)
                #pragma unroll
                for (int r = 0; r < 4; ++r) {
                    float v = fmaf(-2.0f, acc[i][j][r], e);
                    int k = i * 4 + r;
                    float ob = best[k];
                    bool t = v < ob;
                    best[k] = t ? v : ob;
                    sec[k]  = fminf(sec[k], t ? ob : v);
                    bidx[k] = t ? code : bidx[k];
                }
        }
    }

    #pragma unroll
    for (int m = 1; m <= 8; m <<= 1) {
        #pragma unroll
        for (int k = 0; k < 16; ++k) {
            float ob = __shfl_xor(best[k], m, 64);
            float os = __shfl_xor(sec[k],  m, 64);
            int   oi = __shfl_xor(bidx[k], m, 64);
            float ns = fminf(fminf(sec[k], os), fmaxf(best[k], ob));
            bool t = (ob < best[k]) || (ob == best[k] && oi < bidx[k]);
            best[k] = t ? ob : best[k];
            bidx[k] = t ? oi : bidx[k];
            sec[k]  = ns;
        }
    }

    __syncthreads();
    float* mb = (float*)As;
    float* ms = mb + 256;
    int*   mi = (int*)(mb + 512);
    if (l15 == 0) {
        #pragma unroll
        for (int k = 0; k < 16; ++k) {
            int row = w0 * 64 + (k >> 2) * 16 + q * 4 + (k & 3);
            mb[row * 2 + w1] = best[k];
            ms[row * 2 + w1] = sec[k];
            mi[row * 2 + w1] = bidx[k];
        }
    }
    __syncthreads();
    if (tid < 128) {
        float b0 = mb[tid * 2], b1 = mb[tid * 2 + 1];
        float s0 = ms[tid * 2], s1 = ms[tid * 2 + 1];
        int   i0 = mi[tid * 2], i1 = mi[tid * 2 + 1];
        bool t = (b1 < b0) || (b1 == b0 && i1 < i0);
        float bb = t ? b1 : b0;
        int   ii = t ? i1 : i0;
        float ss = fminf(fminf(s0, s1), fmaxf(b0, b1));
        int token = tb * 128 + tid;
        out_idx[token] = ii;
        if (ss - bb < DELTA) {
            int p = atomicAdd(ucount, 1);
            if (p < UCAP) ulist[p] = token;
        }
    }
}

// ---------------- exact fp32 re-scan of uncertain tokens (v2) ----------------
// block = (token-group g of RT tokens) x (code quarter). 256 threads, each owns
// 4 consecutive codes; Et float4 loads are wave-coalesced and L2-resident.
__launch_bounds__(256)
__global__ void k_refine(const float* __restrict__ Z, const float* __restrict__ Et,
                         const float* __restrict__ esq, const int* __restrict__ ulist,
                         const int* __restrict__ ucount, u64* __restrict__ umin) {
    int cnt = *ucount; if (cnt > UCAP) cnt = UCAP;
    const int g   = blockIdx.x >> 2;
    const int qtr = blockIdx.x & 3;
    if (g * RT >= cnt) return;

    __shared__ float zs[RT][256];
    const int tid  = threadIdx.x;
    const int lane = tid & 63;

    #pragma unroll
    for (int t = 0; t < RT; ++t) {
        int u = g * RT + t;
        int tok = ulist[(u < cnt) ? u : g * RT];
        zs[t][tid] = Z[(size_t)tok * EMBED_DIM + tid];
    }
    __syncthreads();

    const int c0 = qtr * 1024 + tid * 4;
    f32x4 acc[RT];
    #pragma unroll
    for (int t = 0; t < RT; ++t) acc[t] = (f32x4)0.0f;

    for (int d4 = 0; d4 < 64; ++d4) {
        f32x4 e0 = *(const f32x4*)(Et + (size_t)(d4 * 4 + 0) * NUM_CODES + c0);
        f32x4 e1 = *(const f32x4*)(Et + (size_t)(d4 * 4 + 1) * NUM_CODES + c0);
        f32x4 e2 = *(const f32x4*)(Et + (size_t)(d4 * 4 + 2) * NUM_CODES + c0);
        f32x4 e3 = *(const f32x4*)(Et + (size_t)(d4 * 4 + 3) * NUM_CODES + c0);
        #pragma unroll
        for (int t = 0; t < RT; ++t) {
            f32x4 z4 = *(const f32x4*)&zs[t][d4 * 4];
            acc[t] += z4.x * e0;
            acc[t] += z4.y * e1;
            acc[t] += z4.z * e2;
            acc[t] += z4.w * e3;
        }
    }

    f32x4 eq = *(const f32x4*)(esq + c0);
    #pragma unroll
    for (int t = 0; t < RT; ++t) {
        // min over this thread's 4 codes, ascending order => smallest-index ties
        u64 p = ~0ull;
        #pragma unroll
        for (int r = 0; r < 4; ++r) {
            float v = fmaf(-2.0f, acc[t][r], eq[r]) + 4096.0f;  // keep positive
            u64 cand = ((u64)__float_as_uint(v) << 32) | (unsigned)(c0 + r);
            p = cand < p ? cand : p;
        }
        #pragma unroll
        for (int m = 1; m <= 32; m <<= 1) {
            u64 o = __shfl_xor(p, m, 64);
            p = o < p ? o : p;
        }
        int u = g * RT + t;
        if (lane == 0 && u < cnt) atomicMin(umin + u, p);
    }
}

__global__ void k_rwrite(const int* __restrict__ ulist, const int* __restrict__ ucount,
                         const u64* __restrict__ umin, int* __restrict__ out_idx) {
    int cnt = *ucount; if (cnt > UCAP) cnt = UCAP;
    int u = blockIdx.x * 256 + threadIdx.x;
    if (u < cnt) out_idx[ulist[u]] = (int)(umin[u] & 0xFFFFFFFFu);
}

// ---------------- gather z_q, loss partials, histogram ----------------
__global__ void k_gather(const float* __restrict__ Z, const float* __restrict__ E,
                         float* __restrict__ out,
                         float* __restrict__ loss_parts, unsigned* __restrict__ hist) {
    int wave = threadIdx.x >> 6, lane = threadIdx.x & 63;
    int token = blockIdx.x * 4 + wave;
    int* idxi = (int*)(out + IDX_OFF);
    int k = idxi[token];
    float4 z = *(const float4*)(Z + (size_t)token * EMBED_DIM + lane * 4);
    float4 qv = *(const float4*)(E + (size_t)k * EMBED_DIM + lane * 4);
    *(float4*)(out + (size_t)token * EMBED_DIM + lane * 4) = qv;
    float dx = qv.x - z.x, dy = qv.y - z.y, dz = qv.z - z.z, dw = qv.w - z.w;
    float s = dx * dx + dy * dy + dz * dz + dw * dw;
    #pragma unroll
    for (int off = 32; off; off >>= 1) s += __shfl_down(s, off, 64);
    if (lane == 0) {
        atomicAdd(loss_parts + (blockIdx.x & 1023), s);
        atomicAdd(hist + k, 1u);
        out[IDX_OFF + token] = (float)k;
    }
}

// ---------------- finalize loss + perplexity ----------------
__global__ void k_final(const float* __restrict__ loss_parts,
                        const unsigned* __restrict__ hist, float* __restrict__ out) {
    __shared__ float red[256];
    int t = threadIdx.x;
    float s = 0.0f;
    for (int i = t; i < 1024; i += 256) s += loss_parts[i];
    red[t] = s;
    __syncthreads();
    #pragma unroll
    for (int off = 128; off; off >>= 1) {
        if (t < off) red[t] += red[t + off];
        __syncthreads();
    }
    float loss = 0.1f * red[0] / (float)(N_TOKENS * EMBED_DIM);

    float h = 0.0f;
    for (int i = t; i < NUM_CODES; i += 256) {
        float p = (float)hist[i] / (float)N_TOKENS;
        h += p * logf(p + 1e-10f);
    }
    __syncthreads();
    red[t] = h;
    __syncthreads();
    #pragma unroll
    for (int off = 128; off; off >>= 1) {
        if (t < off) red[t] += red[t + off];
        __syncthreads();
    }
    if (t == 0) {
        out[LOSS_OFF]     = loss;
        out[LOSS_OFF + 1] = expf(-red[0]);
    }
}

extern "C" void kernel_launch(void* const* d_in, const int* in_sizes, int n_in,
                              void* d_out, int out_size, void* d_ws, size_t ws_size,
                              hipStream_t stream) {
    const float* Z = (const float*)d_in[0];
    const float* E = (const float*)d_in[1];
    float* out = (float*)d_out;
    char*  ob  = (char*)d_out;
    char*  ws  = (char*)d_ws;

    // scratch inside d_out (overwritten by gather/final afterwards):
    _Float16* Zh = (_Float16*)ob;                         // 32 MB
    _Float16* Eh = (_Float16*)(ob + 33554432);            // 2 MB
    float*    Et = (float*)(ob + 33554432 + 2097152);     // 4 MB
    u64*      umin = (u64*)(ob + 33554432 + 2097152 + 4194304); // 128 KB
    int*      idx = (int*)(out + IDX_OFF);

    // small ws scratch (~100 KB)
    float*    esq        = (float*)ws;                    // 16 KB
    int*      ulist      = (int*)(ws + 16384);            // 64 KB
    int*      ucount     = (int*)(ws + 81920);            // 64 B
    float*    loss_parts = (float*)(ws + 81984);          // 4 KB
    unsigned* hist       = (unsigned*)(ws + 86080);       // 16 KB

    hipMemsetAsync(ws + 81920, 0, 64 + 4096 + 16384, stream);
    hipMemsetAsync(umin, 0xFF, (size_t)UCAP * 8, stream);

    k_conv       <<<(N_TOKENS * 32) / 256, 256, 0, stream>>>(Z, Zh, N_TOKENS);
    k_conv       <<<(NUM_CODES * 32) / 256, 256, 0, stream>>>(E, Eh, NUM_CODES);
    k_esq        <<<NUM_CODES, 64, 0, stream>>>(E, esq);
    k_transpose  <<<dim3(NUM_CODES / 32, EMBED_DIM / 32), 256, 0, stream>>>(E, Et);
    k_argmin_mfma<<<N_TOKENS / 128, 256, 0, stream>>>(Zh, Eh, esq, idx, ulist, ucount);
    k_refine     <<<4 * (UCAP / RT), 256, 0, stream>>>(Z, Et, esq, ulist, ucount, umin);
    k_rwrite     <<<UCAP / 256, 256, 0, stream>>>(ulist, ucount, umin, idx);
    k_gather     <<<N_TOKENS / 4, 256, 0, stream>>>(Z, E, out, loss_parts, hist);
    k_final      <<<1, 256, 0, stream>>>(loss_parts, hist, out);
}

// Round 4
// 344.580 us; speedup vs baseline: 7.2268x; 1.1584x over previous
//
#include <hip/hip_runtime.h>

#define N_TOKENS   65536
#define NUM_CODES  4096
#define EMBED_DIM  256

#define IDX_OFF  ((size_t)N_TOKENS * EMBED_DIM)
#define LOSS_OFF (IDX_OFF + N_TOKENS)

#define DELTA 0.2f
#define UCAP  16384
#define RT    8        // tokens per refine block

typedef _Float16 half8 __attribute__((ext_vector_type(8)));
typedef float    f32x4 __attribute__((ext_vector_type(4)));
typedef unsigned long long u64;

__device__ __forceinline__ void gl_lds16(const void* g, void* l) {
    __builtin_amdgcn_global_load_lds(
        (const __attribute__((address_space(1))) unsigned int*)g,
        (__attribute__((address_space(3))) unsigned int*)l, 16, 0, 0);
}

// ---------------- converter: E (f32) -> B-fragment-packed fp16 ----------------
// Eh layout: [ct=code>>4][kc=0..7][lane=q*16+(code&15)] x 16B
//   frag(ct,kc): lane l holds E[ct*16 + (l&15)][kc*32 + (l>>4)*8 + j], j=0..7
__global__ void k_convE(const float* __restrict__ E, _Float16* __restrict__ Eh) {
    int gid = blockIdx.x * 256 + threadIdx.x;   // NUM_CODES*32 threads
    int n  = gid >> 5;
    int kg = gid & 31;
    const float* src = E + (size_t)n * EMBED_DIM + kg * 8;
    float4 a = *(const float4*)src;
    float4 b = *(const float4*)(src + 4);
    int ct = n >> 4, l15 = n & 15, kc = kg >> 2, q = kg & 3;
    int lane = q * 16 + l15;
    half8 hv;
    hv[0]=(_Float16)a.x; hv[1]=(_Float16)a.y; hv[2]=(_Float16)a.z; hv[3]=(_Float16)a.w;
    hv[4]=(_Float16)b.x; hv[5]=(_Float16)b.y; hv[6]=(_Float16)b.z; hv[7]=(_Float16)b.w;
    *(half8*)(Eh + ((size_t)(ct * 8 + kc) * 64 + lane) * 8) = hv;
}

// ---------------- per-code squared norms (exact fp32) ----------------
__global__ void k_esq(const float* __restrict__ E, float* __restrict__ esq) {
    int k = blockIdx.x;
    int l = threadIdx.x;
    float4 v = *(const float4*)(E + (size_t)k * EMBED_DIM + l * 4);
    float s = v.x * v.x + v.y * v.y + v.z * v.z + v.w * v.w;
    #pragma unroll
    for (int off = 32; off; off >>= 1) s += __shfl_down(s, off, 64);
    if (l == 0) esq[k] = s;
}

// ---------------- transpose E -> Et[256][4096] (for refine) ----------------
__global__ void k_transpose(const float* __restrict__ E, float* __restrict__ Et) {
    __shared__ float t[32][33];
    int tx = threadIdx.x & 31, ty = threadIdx.x >> 5;
    int c0 = blockIdx.x * 32, d0 = blockIdx.y * 32;
    #pragma unroll
    for (int i = 0; i < 4; ++i)
        t[ty + 8 * i][tx] = E[(size_t)(c0 + ty + 8 * i) * EMBED_DIM + d0 + tx];
    __syncthreads();
    #pragma unroll
    for (int i = 0; i < 4; ++i)
        Et[(size_t)(d0 + ty + 8 * i) * NUM_CODES + c0 + tx] = t[tx][ty + 8 * i];
}

// ---------------- fused fp16-MFMA distance + argmin/second (v3) ----------------
// block: 256 thr = 4 waves, 128 tokens. wave = 64 tokens (w0 half) x 32 codes (w1 half).
// A-fragments persistent in VGPRs (loaded from fp32 Z, converted once).
// Per it: stage 64 codes x K=256 (32 KB) once, 64 MFMA/wave between barriers.
__launch_bounds__(256, 2)
__global__ void k_argmin_mfma(const float* __restrict__ Z, const _Float16* __restrict__ Eh,
                              const float* __restrict__ esq, int* __restrict__ out_idx,
                              int* __restrict__ ulist, int* __restrict__ ucount) {
    __shared__ __align__(16) _Float16 Bs[16384];   // 32 KB: 64 codes x 256 K
    __shared__ float esq_s[NUM_CODES];             // 16 KB

    const int tid  = threadIdx.x;
    const int lane = tid & 63;
    const int w    = tid >> 6;
    const int w0   = w >> 1;     // token half
    const int w1   = w & 1;      // code half
    const int l15  = lane & 15;
    const int q    = lane >> 4;
    const int tb   = blockIdx.x;

    for (int i = tid; i < NUM_CODES; i += 256) esq_s[i] = esq[i];

    // A-fragments: frag(rt,kc): lane holds Z[tb*128 + w0*64 + rt*16 + l15][kc*32 + q*8 + j]
    half8 A[4][8];
    const float* Zb = Z + ((size_t)tb * 128 + w0 * 64) * EMBED_DIM;
    #pragma unroll
    for (int rt = 0; rt < 4; ++rt) {
        const float* Zr = Zb + (rt * 16 + l15) * EMBED_DIM + q * 8;
        #pragma unroll
        for (int kc = 0; kc < 8; ++kc) {
            float4 a = *(const float4*)(Zr + kc * 32);
            float4 b = *(const float4*)(Zr + kc * 32 + 4);
            half8 hv;
            hv[0]=(_Float16)a.x; hv[1]=(_Float16)a.y; hv[2]=(_Float16)a.z; hv[3]=(_Float16)a.w;
            hv[4]=(_Float16)b.x; hv[5]=(_Float16)b.y; hv[6]=(_Float16)b.z; hv[7]=(_Float16)b.w;
            A[rt][kc] = hv;
        }
    }

    float best[16], sec[16];
    int   bidx[16];
    #pragma unroll
    for (int k = 0; k < 16; ++k) { best[k] = 1e30f; sec[k] = 1e30f; bidx[k] = 0; }

    const int cb = w1 * 2;   // this wave's 2 ct of the it-tile's 4

    for (int it = 0; it < NUM_CODES / 64; ++it) {
        __syncthreads();
        // stage 32 KB: 8 x 1KB per wave, layout identical to Eh (fragment-linear)
        const _Float16* src = Eh + (size_t)it * 16384 + (w * 8) * 512 + lane * 8;
        #pragma unroll
        for (int s = 0; s < 8; ++s)
            gl_lds16(src + s * 512, Bs + (w * 8 + s) * 512);
        __syncthreads();

        f32x4 acc[4][2];
        #pragma unroll
        for (int rt = 0; rt < 4; ++rt) { acc[rt][0] = (f32x4)0.0f; acc[rt][1] = (f32x4)0.0f; }

        #pragma unroll
        for (int kc = 0; kc < 8; ++kc) {
            half8 bf0 = *(const half8*)(Bs + ((cb + 0) * 8 + kc) * 512 + lane * 8);
            half8 bf1 = *(const half8*)(Bs + ((cb + 1) * 8 + kc) * 512 + lane * 8);
            #pragma unroll
            for (int rt = 0; rt < 4; ++rt) {
                acc[rt][0] = __builtin_amdgcn_mfma_f32_16x16x32_f16(A[rt][kc], bf0, acc[rt][0], 0, 0, 0);
                acc[rt][1] = __builtin_amdgcn_mfma_f32_16x16x32_f16(A[rt][kc], bf1, acc[rt][1], 0, 0, 0);
            }
        }

        // epilogue: d2 = esq - 2*dot; codes ascending (c=0 then c=1)
        int code0 = it * 64 + cb * 16 + l15;
        #pragma unroll
        for (int c = 0; c < 2; ++c) {
            float e  = esq_s[code0 + c * 16];
            int code = code0 + c * 16;
            #pragma unroll
            for (int rt = 0; rt < 4; ++rt)
                #pragma unroll
                for (int r = 0; r < 4; ++r) {
                    float v = fmaf(-2.0f, acc[rt][c][r], e);
                    int k = rt * 4 + r;
                    float ob = best[k];
                    bool t = v < ob;
                    best[k] = t ? v : ob;
                    sec[k]  = fminf(sec[k], t ? ob : v);
                    bidx[k] = t ? code : bidx[k];
                }
        }
    }

    // in-wave reduce over the 16 col-lanes (l15) of each quad group
    #pragma unroll
    for (int m = 1; m <= 8; m <<= 1) {
        #pragma unroll
        for (int k = 0; k < 16; ++k) {
            float ob = __shfl_xor(best[k], m, 64);
            float os = __shfl_xor(sec[k],  m, 64);
            int   oi = __shfl_xor(bidx[k], m, 64);
            float ns = fminf(fminf(sec[k], os), fmaxf(best[k], ob));
            bool t = (ob < best[k]) || (ob == best[k] && oi < bidx[k]);
            best[k] = t ? ob : best[k];
            bidx[k] = t ? oi : bidx[k];
            sec[k]  = ns;
        }
    }

    // cross-code-half merge via LDS (reuse Bs)
    __syncthreads();
    float* mb = (float*)Bs;          // [128][2]
    float* ms = mb + 256;
    int*   mi = (int*)(mb + 512);
    if (l15 == 0) {
        #pragma unroll
        for (int k = 0; k < 16; ++k) {
            int row = w0 * 64 + (k >> 2) * 16 + q * 4 + (k & 3);
            mb[row * 2 + w1] = best[k];
            ms[row * 2 + w1] = sec[k];
            mi[row * 2 + w1] = bidx[k];
        }
    }
    __syncthreads();
    if (tid < 128) {
        float b0 = mb[tid * 2], b1 = mb[tid * 2 + 1];
        float s0 = ms[tid * 2], s1 = ms[tid * 2 + 1];
        int   i0 = mi[tid * 2], i1 = mi[tid * 2 + 1];
        bool t = (b1 < b0) || (b1 == b0 && i1 < i0);
        float bb = t ? b1 : b0;
        int   ii = t ? i1 : i0;
        float ss = fminf(fminf(s0, s1), fmaxf(b0, b1));
        int token = tb * 128 + tid;
        out_idx[token] = ii;
        if (ss - bb < DELTA) {
            int p = atomicAdd(ucount, 1);
            if (p < UCAP) ulist[p] = token;
        }
    }
}

// ---------------- exact fp32 re-scan of uncertain tokens ----------------
__launch_bounds__(256)
__global__ void k_refine(const float* __restrict__ Z, const float* __restrict__ Et,
                         const float* __restrict__ esq, const int* __restrict__ ulist,
                         const int* __restrict__ ucount, u64* __restrict__ umin) {
    int cnt = *ucount; if (cnt > UCAP) cnt = UCAP;
    const int g   = blockIdx.x >> 2;
    const int qtr = blockIdx.x & 3;
    if (g * RT >= cnt) return;

    __shared__ float zs[RT][256];
    const int tid  = threadIdx.x;
    const int lane = tid & 63;

    #pragma unroll
    for (int t = 0; t < RT; ++t) {
        int u = g * RT + t;
        int tok = ulist[(u < cnt) ? u : g * RT];
        zs[t][tid] = Z[(size_t)tok * EMBED_DIM + tid];
    }
    __syncthreads();

    const int c0 = qtr * 1024 + tid * 4;
    f32x4 acc[RT];
    #pragma unroll
    for (int t = 0; t < RT; ++t) acc[t] = (f32x4)0.0f;

    for (int d4 = 0; d4 < 64; ++d4) {
        f32x4 e0 = *(const f32x4*)(Et + (size_t)(d4 * 4 + 0) * NUM_CODES + c0);
        f32x4 e1 = *(const f32x4*)(Et + (size_t)(d4 * 4 + 1) * NUM_CODES + c0);
        f32x4 e2 = *(const f32x4*)(Et + (size_t)(d4 * 4 + 2) * NUM_CODES + c0);
        f32x4 e3 = *(const f32x4*)(Et + (size_t)(d4 * 4 + 3) * NUM_CODES + c0);
        #pragma unroll
        for (int t = 0; t < RT; ++t) {
            f32x4 z4 = *(const f32x4*)&zs[t][d4 * 4];
            acc[t] += z4.x * e0;
            acc[t] += z4.y * e1;
            acc[t] += z4.z * e2;
            acc[t] += z4.w * e3;
        }
    }

    f32x4 eq = *(const f32x4*)(esq + c0);
    #pragma unroll
    for (int t = 0; t < RT; ++t) {
        u64 p = ~0ull;
        #pragma unroll
        for (int r = 0; r < 4; ++r) {
            float v = fmaf(-2.0f, acc[t][r], eq[r]) + 4096.0f;
            u64 cand = ((u64)__float_as_uint(v) << 32) | (unsigned)(c0 + r);
            p = cand < p ? cand : p;
        }
        #pragma unroll
        for (int m = 1; m <= 32; m <<= 1) {
            u64 o = __shfl_xor(p, m, 64);
            p = o < p ? o : p;
        }
        int u = g * RT + t;
        if (lane == 0 && u < cnt) atomicMin(umin + u, p);
    }
}

__global__ void k_rwrite(const int* __restrict__ ulist, const int* __restrict__ ucount,
                         const u64* __restrict__ umin, int* __restrict__ out_idx) {
    int cnt = *ucount; if (cnt > UCAP) cnt = UCAP;
    int u = blockIdx.x * 256 + threadIdx.x;
    if (u < cnt) out_idx[ulist[u]] = (int)(umin[u] & 0xFFFFFFFFu);
}

// ---------------- gather z_q, loss partials, histogram ----------------
__global__ void k_gather(const float* __restrict__ Z, const float* __restrict__ E,
                         float* __restrict__ out,
                         float* __restrict__ loss_parts, unsigned* __restrict__ hist) {
    int wave = threadIdx.x >> 6, lane = threadIdx.x & 63;
    int token = blockIdx.x * 4 + wave;
    int* idxi = (int*)(out + IDX_OFF);
    int k = idxi[token];
    float4 z = *(const float4*)(Z + (size_t)token * EMBED_DIM + lane * 4);
    float4 qv = *(const float4*)(E + (size_t)k * EMBED_DIM + lane * 4);
    *(float4*)(out + (size_t)token * EMBED_DIM + lane * 4) = qv;
    float dx = qv.x - z.x, dy = qv.y - z.y, dz = qv.z - z.z, dw = qv.w - z.w;
    float s = dx * dx + dy * dy + dz * dz + dw * dw;
    #pragma unroll
    for (int off = 32; off; off >>= 1) s += __shfl_down(s, off, 64);
    if (lane == 0) {
        atomicAdd(loss_parts + (blockIdx.x & 1023), s);
        atomicAdd(hist + k, 1u);
        out[IDX_OFF + token] = (float)k;
    }
}

// ---------------- finalize loss + perplexity ----------------
__global__ void k_final(const float* __restrict__ loss_parts,
                        const unsigned* __restrict__ hist, float* __restrict__ out) {
    __shared__ float red[256];
    int t = threadIdx.x;
    float s = 0.0f;
    for (int i = t; i < 1024; i += 256) s += loss_parts[i];
    red[t] = s;
    __syncthreads();
    #pragma unroll
    for (int off = 128; off; off >>= 1) {
        if (t < off) red[t] += red[t + off];
        __syncthreads();
    }
    float loss = 0.1f * red[0] / (float)(N_TOKENS * EMBED_DIM);

    float h = 0.0f;
    for (int i = t; i < NUM_CODES; i += 256) {
        float p = (float)hist[i] / (float)N_TOKENS;
        h += p * logf(p + 1e-10f);
    }
    __syncthreads();
    red[t] = h;
    __syncthreads();
    #pragma unroll
    for (int off = 128; off; off >>= 1) {
        if (t < off) red[t] += red[t + off];
        __syncthreads();
    }
    if (t == 0) {
        out[LOSS_OFF]     = loss;
        out[LOSS_OFF + 1] = expf(-red[0]);
    }
}

extern "C" void kernel_launch(void* const* d_in, const int* in_sizes, int n_in,
                              void* d_out, int out_size, void* d_ws, size_t ws_size,
                              hipStream_t stream) {
    const float* Z = (const float*)d_in[0];
    const float* E = (const float*)d_in[1];
    float* out = (float*)d_out;
    char*  ob  = (char*)d_out;
    char*  ws  = (char*)d_ws;

    // scratch in d_out's upper z_q region (overwritten by gather afterwards):
    _Float16* Eh   = (_Float16*)(ob + 50331648);          // 48 MB: 2 MB packed
    float*    Et   = (float*)(ob + 54525952);             // 52 MB: 4 MB
    u64*      umin = (u64*)(ob + 58720256);               // 56 MB: 128 KB
    int*      idx  = (int*)(out + IDX_OFF);

    // small ws scratch (~100 KB)
    float*    esq        = (float*)ws;                    // 16 KB
    int*      ulist      = (int*)(ws + 16384);            // 64 KB
    int*      ucount     = (int*)(ws + 81920);            // 64 B
    float*    loss_parts = (float*)(ws + 81984);          // 4 KB
    unsigned* hist       = (unsigned*)(ws + 86080);       // 16 KB

    hipMemsetAsync(ws + 81920, 0, 64 + 4096 + 16384, stream);
    hipMemsetAsync(umin, 0xFF, (size_t)UCAP * 8, stream);

    k_convE      <<<(NUM_CODES * 32) / 256, 256, 0, stream>>>(E, Eh);
    k_esq        <<<NUM_CODES, 64, 0, stream>>>(E, esq);
    k_transpose  <<<dim3(NUM_CODES / 32, EMBED_DIM / 32), 256, 0, stream>>>(E, Et);
    k_argmin_mfma<<<N_TOKENS / 128, 256, 0, stream>>>(Z, Eh, esq, idx, ulist, ucount);
    k_refine     <<<4 * (UCAP / RT), 256, 0, stream>>>(Z, Et, esq, ulist, ucount, umin);
    k_rwrite     <<<UCAP / 256, 256, 0, stream>>>(ulist, ucount, umin, idx);
    k_gather     <<<N_TOKENS / 4, 256, 0, stream>>>(Z, E, out, loss_parts, hist);
    k_final      <<<1, 256, 0, stream>>>(loss_parts, hist, out);
}